// Round 6
// baseline (101.875 us; speedup 1.0000x reference)
//
#include <hip/hip_runtime.h>

#define TIN   4096
#define FIN   128
#define NB    64
#define FOUT  128
#define TOUT  6144
// per-batch ws layout (ints): [0,TIN) seg_start, [TIN,2TIN) tgt, [2TIN,3TIN) cum_end, [3TIN] n_segs, [3TIN+1] T_total
#define SEG_STRIDE (3 * TIN + 64)

#define TB    512            // output t per block (8 per lane in compute)
#define SPAN  416            // staged input window (floats per f-row)
#define SPANP (SPAN + 4)     // +4 pad so the speculative +1 tap stays in-array
#define SPAN4 (SPAN / 4)
#define ZSPL  2              // f-dim split across blockIdx.z
#define FPB   (FOUT / ZSPL)  // 64 f-rows per block
#define RPW   (FPB / 4)      // 16 rows per wave

typedef float f32x4 __attribute__((ext_vector_type(4)));

// inclusive scan within a 64-lane wave (no barriers)
__device__ __forceinline__ int wave_iscan(int v, int lane) {
#pragma unroll
    for (int d = 1; d < 64; d <<= 1) {
        int n = __shfl_up(v, d, 64);
        if (lane >= d) v += n;
    }
    return v;
}

// block-wide (256 threads = 4 waves) inclusive scan; 2 barriers total
__device__ __forceinline__ int block_scan_incl(int v, int tid, int* wsum4, int* total) {
    const int lane = tid & 63, wid = tid >> 6;
    int incl = wave_iscan(v, lane);
    if (lane == 63) wsum4[wid] = incl;
    __syncthreads();
    int woff = 0;
#pragma unroll
    for (int i = 0; i < 3; ++i) woff += (i < wid) ? wsum4[i] : 0;
    *total = wsum4[0] + wsum4[1] + wsum4[2] + wsum4[3];
    __syncthreads();
    return incl + woff;
}

__global__ __launch_bounds__(256) void seg_kernel(const int* __restrict__ mask,
                                                  int* __restrict__ ws) {
    __shared__ int seg_start_sh[TIN];  // packed: start | (voiced<<16)
    __shared__ int tgt_sh[TIN];
    __shared__ int wsum4[4];

    const int b = blockIdx.x;
    const int tid = threadIdx.x;
    const int* mrow = mask + (size_t)b * TIN;

    for (int i = tid; i < TIN; i += 256) tgt_sh[i] = 0;

    // ---- Phase A: change flags -> segment starts; voiced count ----
    const int base = tid * 16;
    int m[16];
#pragma unroll
    for (int j = 0; j < 4; ++j) {
        int4 v = ((const int4*)(mrow + base))[j];
        m[4 * j + 0] = v.x; m[4 * j + 1] = v.y; m[4 * j + 2] = v.z; m[4 * j + 3] = v.w;
    }
    const int prev = (base == 0) ? 0 : mrow[base - 1];

    int incl[16];
    int run = 0, vsum = 0;
#pragma unroll
    for (int j = 0; j < 16; ++j) {
        int pm = (j == 0) ? prev : m[j - 1];
        int c = (base + j == 0) ? 1 : ((m[j] != pm) ? 1 : 0);
        run += c;
        incl[j] = run;
        vsum += m[j];
    }
    // packed scan: high16 = segment count, low16 = voiced count (totals <= 4096, no carry)
    int tot_packed;
    int sp = block_scan_incl((run << 16) | vsum, tid, wsum4, &tot_packed);
    const int n_segs  = tot_packed >> 16;
    const int total_v = tot_packed & 0xFFFF;
    int off = (sp >> 16) - run;
#pragma unroll
    for (int j = 0; j < 16; ++j) {
        int c = (j == 0) ? incl[0] : (incl[j] - incl[j - 1]);
        if (c) seg_start_sh[off + incl[j] - 1] = (base + j) | (m[j] << 16);
    }
    __syncthreads();

    // ---- Phase B: rates (match reference f32 op order) ----
    const float len_v = (float)total_v;
    const float len_uv = (float)TIN - len_v;
    const float ratiof = (float)(0.7 / 0.3);
    const bool both = (len_v > 0.f) && (len_uv > 0.f);
    float rv;
    if (both)              rv = (float)TOUT / (len_v + len_uv / ratiof);
    else if (len_v > 0.f)  rv = (float)TOUT / fmaxf(len_v, 1.f);
    else                   rv = (float)TOUT / fmaxf(len_uv, 1.f);
    const float ruv = both ? (rv / ratiof) : rv;

    // ---- Phase C: per-segment target lengths (last takes remainder) ----
    int lsum = 0;
    for (int s = tid; s < n_segs; s += 256) {
        int v = seg_start_sh[s];
        int st = v & 0xFFFF;
        int voiced = v >> 16;
        int en = (s + 1 < n_segs) ? (seg_start_sh[s + 1] & 0xFFFF) : TIN;
        int len = en - st;
        float scale = voiced ? rv : ruv;
        int tg = (int)fmaxf(1.0f, rintf(scale * (float)len));  // rintf == round-half-even == jnp.round
        if (s != n_segs - 1) { tgt_sh[s] = tg; lsum += tg; }
    }
    int sum_others;
    block_scan_incl(lsum, tid, wsum4, &sum_others);
    if (tid == 0) tgt_sh[n_segs - 1] = max(1, TOUT - sum_others);
    __syncthreads();

    // ---- Phase D: inclusive scan of tgt -> cum_end ----
    int tincl[16];
    int trun = 0;
#pragma unroll
    for (int j = 0; j < 16; ++j) { trun += tgt_sh[base + j]; tincl[j] = trun; }
    int ttot;
    int tsincl = block_scan_incl(trun, tid, wsum4, &ttot);
    int toff = tsincl - trun;

    int* wbp = ws + (size_t)b * SEG_STRIDE;
#pragma unroll
    for (int j = 0; j < 16; ++j) {
        int i = base + j;
        if (i < n_segs) wbp[2 * TIN + i] = toff + tincl[j];
    }
    for (int i = tid; i < n_segs; i += 256) {
        wbp[i]       = seg_start_sh[i] & 0xFFFF;
        wbp[TIN + i] = tgt_sh[i];
    }
    if (tid == 0) { wbp[3 * TIN] = n_segs; wbp[3 * TIN + 1] = ttot; }
}

__device__ __forceinline__ void map_concat(int k, const unsigned short* __restrict__ cum16,
                                           const int* __restrict__ wbp, int n_segs,
                                           int& i0, int& i1, float& w) {
    // first index with cum_end[idx] > k  (searchsorted side='right')
    int lo = 0, hi = n_segs;
    while (lo < hi) {
        int mid = (lo + hi) >> 1;
        if ((int)cum16[mid] > k) hi = mid; else lo = mid + 1;
    }
    int s = min(lo, n_segs - 1);

    int ce = (int)cum16[s];
    int tg = wbp[TIN + s];
    int cs = ce - tg;
    int st = wbp[s];
    int en = (s + 1 < n_segs) ? wbp[s + 1] : TIN;
    float L  = (float)(en - st);
    float TL = fmaxf((float)tg, 1.f);
    float src = fmaxf(((float)(k - cs) + 0.5f) * (L / TL) - 0.5f, 0.f);
    float x0 = floorf(src);
    w = src - x0;
    float x1 = fminf(x0 + 1.f, L - 1.f);
    i0 = st + (int)x0;
    i1 = st + (int)x1;
}

__global__ __launch_bounds__(256) void resample_kernel(const float* __restrict__ mel,
                                                       const int* __restrict__ ws,
                                                       float* __restrict__ out) {
    // union region: phase 1-2 = cum16 (8 KB); phase 3+ = per-wave double-buffered stage (13.4 KB)
    __shared__ __align__(16) unsigned char upool[4 * 2 * SPANP * 4];
    __shared__ unsigned int mapP[TB];     // packed: a0(13b) | sa<<13 | b0<<16(13b) | sb<<29  (absolute idx)
    __shared__ float mapW[4][TB];         // W0..W3 per t
    __shared__ int bcast[2];

    unsigned short* cum16 = (unsigned short*)upool;

    const int b = blockIdx.y;
    const int tid = threadIdx.x;
    const int wid = tid >> 6, lane = tid & 63;
    const int tbase = blockIdx.x * TB;
    const int fz = blockIdx.z * FPB;

    const int* wbp = ws + (size_t)b * SEG_STRIDE;
    const int n_segs  = wbp[3 * TIN];
    const int T_total = wbp[3 * TIN + 1];

    for (int i = tid; i < n_segs; i += 256) cum16[i] = (unsigned short)wbp[2 * TIN + i];
    __syncthreads();

    const bool identity = (T_total == TOUT);  // per-batch uniform -> no divergence

    // ---- cooperative map build: 2 t per thread, written to LDS map table ----
#pragma unroll
    for (int j = 0; j < 2; ++j) {
        const int tt = 2 * tid + j;
        const int t = tbase + tt;
        int k0, k1; float lam;
        if (identity) {
            k0 = t; k1 = t; lam = 0.f;   // (t+0.5)*1.0-0.5 == t exactly in fp32
        } else {
            float sc = fmaxf(((float)t + 0.5f) * ((float)T_total / (float)TOUT) - 0.5f, 0.f);
            k0 = (int)floorf(sc);
            k1 = min(k0 + 1, T_total - 1);
            lam = sc - (float)k0;
        }
        int a0, a1, bb0, bb1; float wa, wb;
        map_concat(k0, cum16, wbp, n_segs, a0, a1, wa);
        if (identity) { bb0 = a0; bb1 = a1; wb = wa; }
        else          map_concat(k1, cum16, wbp, n_segs, bb0, bb1, wb);

        mapP[tt] = (unsigned)a0 | ((a1 != a0) ? (1u << 13) : 0u)
                 | ((unsigned)bb0 << 16) | ((bb1 != bb0) ? (1u << 29) : 0u);
        mapW[0][tt] = (1.f - lam) * (1.f - wa);
        mapW[1][tt] = (1.f - lam) * wa;
        mapW[2][tt] = lam * (1.f - wb);
        mapW[3][tt] = lam * wb;

        if (tid == 0 && j == 0)   bcast[0] = a0;
        if (tid == 255 && j == 1) bcast[1] = max(a1, bb1);
    }
    __syncthreads();   // maps visible; cum16 region now dead -> reusable as stage

    const int x_lo = bcast[0] & ~3;             // align for float4 staging
    const int x_hi = bcast[1];
    const int n4 = (x_hi + 1 - x_lo + 3) >> 2;  // float4s per f-row

    // ---- per-lane map readback: this lane owns 8 consecutive t ----
    const int mt = lane * 8;
    int a0r[8], b0r[8];
    bool sa[8], sb[8];
    float w0[8], w1[8], w2[8], w3[8];
#pragma unroll
    for (int j = 0; j < 8; ++j) {
        unsigned mp = mapP[mt + j];
        a0r[j] = (int)(mp & 0x1FFF);
        sa[j]  = (mp >> 13) & 1;
        b0r[j] = (int)((mp >> 16) & 0x1FFF);
        sb[j]  = (mp >> 29) & 1;
        w0[j] = mapW[0][mt + j]; w1[j] = mapW[1][mt + j];
        w2[j] = mapW[2][mt + j]; w3[j] = mapW[3][mt + j];
    }

    if (n4 <= SPAN4) {
        // ---- fast path: wave-private double-buffered stage; NO barriers below ----
#pragma unroll
        for (int j = 0; j < 8; ++j) { a0r[j] -= x_lo; b0r[j] -= x_lo; }

        float* st0 = (float*)upool + (wid * 2 + 0) * SPANP;
        float* st1 = (float*)upool + (wid * 2 + 1) * SPANP;
        const bool p0 = lane < n4;
        const bool p1 = (lane + 64) < n4;

        f32x4 R0, R1;
        {
            const f32x4* gs = (const f32x4*)(mel + ((size_t)(b * FIN + fz + wid)) * TIN + x_lo);
            if (p0) R0 = gs[lane];
            if (p1) R1 = gs[lane + 64];
            if (p0) ((f32x4*)st0)[lane] = R0;
            if (p1) ((f32x4*)st0)[lane + 64] = R1;
        }

        float* orow0 = out + ((size_t)(b * FOUT + fz + wid)) * TOUT + tbase + lane * 8;

        for (int r = 0; r < RPW; ++r) {
            const float* cur = (r & 1) ? st1 : st0;
            float* nxt = (r & 1) ? st0 : st1;

            if (r + 1 < RPW) {   // issue next row's loads early
                const f32x4* gs = (const f32x4*)(mel + ((size_t)(b * FIN + fz + wid + 4 * (r + 1))) * TIN + x_lo);
                if (p0) R0 = gs[lane];
                if (p1) R1 = gs[lane + 64];
            }

            float vout[8];
            if (identity) {
#pragma unroll
                for (int j = 0; j < 8; ++j) {
                    float xa = cur[a0r[j]], ya = cur[a0r[j] + 1];   // ds_read2_b32
                    vout[j] = w0[j] * xa + w1[j] * (sa[j] ? ya : xa);
                }
            } else {
#pragma unroll
                for (int j = 0; j < 8; ++j) {
                    float xa = cur[a0r[j]], ya = cur[a0r[j] + 1];
                    float xb = cur[b0r[j]], yb = cur[b0r[j] + 1];
                    vout[j] = w0[j] * xa + w1[j] * (sa[j] ? ya : xa)
                            + w2[j] * xb + w3[j] * (sb[j] ? yb : xb);
                }
            }
            f32x4 v0 = {vout[0], vout[1], vout[2], vout[3]};
            f32x4 v1 = {vout[4], vout[5], vout[6], vout[7]};
            float* orow = orow0 + (size_t)(4 * r) * TOUT;
            ((f32x4*)orow)[0] = v0;
            ((f32x4*)orow)[1] = v1;

            if (r + 1 < RPW) {   // write other half; this wave's readers of cur already done
                if (p0) ((f32x4*)nxt)[lane] = R0;
                if (p1) ((f32x4*)nxt)[lane + 64] = R1;
            }
        }
    } else {
        // ---- fallback (pathological span): direct global gathers via absolute maps ----
        for (int r = 0; r < RPW; ++r) {
            const float* g = mel + ((size_t)(b * FIN + fz + wid + 4 * r)) * TIN;
            float vout[8];
#pragma unroll
            for (int j = 0; j < 8; ++j) {
                float va = w0[j] * g[a0r[j]] + w1[j] * g[a0r[j] + (sa[j] ? 1 : 0)];
                va += w2[j] * g[b0r[j]] + w3[j] * g[b0r[j] + (sb[j] ? 1 : 0)];
                vout[j] = va;
            }
            float* orow = out + ((size_t)(b * FOUT + fz + wid + 4 * r)) * TOUT + tbase + lane * 8;
            f32x4 v0 = {vout[0], vout[1], vout[2], vout[3]};
            f32x4 v1 = {vout[4], vout[5], vout[6], vout[7]};
            ((f32x4*)orow)[0] = v0;
            ((f32x4*)orow)[1] = v1;
        }
    }
}

extern "C" void kernel_launch(void* const* d_in, const int* in_sizes, int n_in,
                              void* d_out, int out_size, void* d_ws, size_t ws_size,
                              hipStream_t stream) {
    const float* mel = (const float*)d_in[0];
    const int* mask  = (const int*)d_in[1];
    float* out = (float*)d_out;
    int* ws = (int*)d_ws;

    seg_kernel<<<NB, 256, 0, stream>>>(mask, ws);

    dim3 grid(TOUT / TB, NB, ZSPL);
    resample_kernel<<<grid, 256, 0, stream>>>(mel, ws, out);
}

// Round 7
// 79.984 us; speedup vs baseline: 1.2737x; 1.2737x over previous
//
#include <hip/hip_runtime.h>

#define TIN   4096
#define FIN   128
#define NB    64
#define FOUT  128
#define TOUT  6144
// per-batch ws layout (ints): [0,TIN) seg_start, [TIN,2TIN) tgt, [2TIN,3TIN) cum_end, [3TIN] n_segs, [3TIN+1] T_total
#define SEG_STRIDE (3 * TIN + 64)

#define TB    512            // output t per block (2 per thread)
#define SPAN  416            // staged input window (floats per f-row)
#define SPANP (SPAN + 4)     // +4 pad so the speculative +1 tap stays in-array
#define SPAN4 (SPAN / 4)
#define FG    8              // f-rows per chunk
#define ZSPL  4              // f-dim split across blockIdx.z
#define FPB   (FOUT / ZSPL)  // 32 f-rows per block
#define NCH   (FPB / FG)     // 4 chunks per block

typedef float f32x4 __attribute__((ext_vector_type(4)));
typedef float f32x2 __attribute__((ext_vector_type(2)));

// inclusive scan within a 64-lane wave (no barriers)
__device__ __forceinline__ int wave_iscan(int v, int lane) {
#pragma unroll
    for (int d = 1; d < 64; d <<= 1) {
        int n = __shfl_up(v, d, 64);
        if (lane >= d) v += n;
    }
    return v;
}

// block-wide (256 threads = 4 waves) inclusive scan; 2 barriers total
__device__ __forceinline__ int block_scan_incl(int v, int tid, int* wsum4, int* total) {
    const int lane = tid & 63, wid = tid >> 6;
    int incl = wave_iscan(v, lane);
    if (lane == 63) wsum4[wid] = incl;
    __syncthreads();
    int woff = 0;
#pragma unroll
    for (int i = 0; i < 3; ++i) woff += (i < wid) ? wsum4[i] : 0;
    *total = wsum4[0] + wsum4[1] + wsum4[2] + wsum4[3];
    __syncthreads();
    return incl + woff;
}

__global__ __launch_bounds__(256) void seg_kernel(const int* __restrict__ mask,
                                                  int* __restrict__ ws) {
    __shared__ int seg_start_sh[TIN];  // packed: start | (voiced<<16)
    __shared__ int tgt_sh[TIN];
    __shared__ int wsum4[4];

    const int b = blockIdx.x;
    const int tid = threadIdx.x;
    const int* mrow = mask + (size_t)b * TIN;

    for (int i = tid; i < TIN; i += 256) tgt_sh[i] = 0;

    // ---- Phase A: change flags -> segment starts; voiced count ----
    const int base = tid * 16;
    int m[16];
#pragma unroll
    for (int j = 0; j < 4; ++j) {
        int4 v = ((const int4*)(mrow + base))[j];
        m[4 * j + 0] = v.x; m[4 * j + 1] = v.y; m[4 * j + 2] = v.z; m[4 * j + 3] = v.w;
    }
    const int prev = (base == 0) ? 0 : mrow[base - 1];

    int incl[16];
    int run = 0, vsum = 0;
#pragma unroll
    for (int j = 0; j < 16; ++j) {
        int pm = (j == 0) ? prev : m[j - 1];
        int c = (base + j == 0) ? 1 : ((m[j] != pm) ? 1 : 0);
        run += c;
        incl[j] = run;
        vsum += m[j];
    }
    // packed scan: high16 = segment count, low16 = voiced count (totals <= 4096, no carry)
    int tot_packed;
    int sp = block_scan_incl((run << 16) | vsum, tid, wsum4, &tot_packed);
    const int n_segs  = tot_packed >> 16;
    const int total_v = tot_packed & 0xFFFF;
    int off = (sp >> 16) - run;
#pragma unroll
    for (int j = 0; j < 16; ++j) {
        int c = (j == 0) ? incl[0] : (incl[j] - incl[j - 1]);
        if (c) seg_start_sh[off + incl[j] - 1] = (base + j) | (m[j] << 16);
    }
    __syncthreads();

    // ---- Phase B: rates (match reference f32 op order) ----
    const float len_v = (float)total_v;
    const float len_uv = (float)TIN - len_v;
    const float ratiof = (float)(0.7 / 0.3);
    const bool both = (len_v > 0.f) && (len_uv > 0.f);
    float rv;
    if (both)              rv = (float)TOUT / (len_v + len_uv / ratiof);
    else if (len_v > 0.f)  rv = (float)TOUT / fmaxf(len_v, 1.f);
    else                   rv = (float)TOUT / fmaxf(len_uv, 1.f);
    const float ruv = both ? (rv / ratiof) : rv;

    // ---- Phase C: per-segment target lengths (last takes remainder) ----
    int lsum = 0;
    for (int s = tid; s < n_segs; s += 256) {
        int v = seg_start_sh[s];
        int st = v & 0xFFFF;
        int voiced = v >> 16;
        int en = (s + 1 < n_segs) ? (seg_start_sh[s + 1] & 0xFFFF) : TIN;
        int len = en - st;
        float scale = voiced ? rv : ruv;
        int tg = (int)fmaxf(1.0f, rintf(scale * (float)len));  // rintf == round-half-even == jnp.round
        if (s != n_segs - 1) { tgt_sh[s] = tg; lsum += tg; }
    }
    int sum_others;
    block_scan_incl(lsum, tid, wsum4, &sum_others);
    if (tid == 0) tgt_sh[n_segs - 1] = max(1, TOUT - sum_others);
    __syncthreads();

    // ---- Phase D: inclusive scan of tgt -> cum_end ----
    int tincl[16];
    int trun = 0;
#pragma unroll
    for (int j = 0; j < 16; ++j) { trun += tgt_sh[base + j]; tincl[j] = trun; }
    int ttot;
    int tsincl = block_scan_incl(trun, tid, wsum4, &ttot);
    int toff = tsincl - trun;

    int* wbp = ws + (size_t)b * SEG_STRIDE;
#pragma unroll
    for (int j = 0; j < 16; ++j) {
        int i = base + j;
        if (i < n_segs) wbp[2 * TIN + i] = toff + tincl[j];
    }
    for (int i = tid; i < n_segs; i += 256) {
        wbp[i]       = seg_start_sh[i] & 0xFFFF;
        wbp[TIN + i] = tgt_sh[i];
    }
    if (tid == 0) { wbp[3 * TIN] = n_segs; wbp[3 * TIN + 1] = ttot; }
}

__device__ __forceinline__ void map_concat(int k, const unsigned short* __restrict__ cum16,
                                           const int* __restrict__ wbp, int n_segs,
                                           int& i0, int& i1, float& w) {
    // first index with cum_end[idx] > k  (searchsorted side='right')
    int lo = 0, hi = n_segs;
    while (lo < hi) {
        int mid = (lo + hi) >> 1;
        if ((int)cum16[mid] > k) hi = mid; else lo = mid + 1;
    }
    int s = min(lo, n_segs - 1);

    int ce = (int)cum16[s];
    int tg = wbp[TIN + s];
    int cs = ce - tg;
    int st = wbp[s];
    int en = (s + 1 < n_segs) ? wbp[s + 1] : TIN;
    float L  = (float)(en - st);
    float TL = fmaxf((float)tg, 1.f);
    float src = fmaxf(((float)(k - cs) + 0.5f) * (L / TL) - 0.5f, 0.f);
    float x0 = floorf(src);
    w = src - x0;
    float x1 = fminf(x0 + 1.f, L - 1.f);
    i0 = st + (int)x0;
    i1 = st + (int)x1;
}

__global__ __launch_bounds__(256) void resample_kernel(const float* __restrict__ mel,
                                                       const int* __restrict__ ws,
                                                       float* __restrict__ out) {
    __shared__ unsigned short cum16[TIN];       // 8 KB
    __shared__ float stage[2][FG * SPANP];      // 2 x ~13 KB (padded rows)
    __shared__ int bcast[2];

    const int b = blockIdx.y;
    const int tid = threadIdx.x;
    const int t0 = blockIdx.x * TB + tid * 2;   // 2 consecutive t per thread
    const int fz = blockIdx.z * FPB;            // this block's f-range start

    const int* wbp = ws + (size_t)b * SEG_STRIDE;
    const int n_segs  = wbp[3 * TIN];
    const int T_total = wbp[3 * TIN + 1];

    for (int i = tid; i < n_segs; i += 256) cum16[i] = (unsigned short)wbp[2 * TIN + i];
    __syncthreads();

    const bool identity = (T_total == TOUT);  // per-batch uniform -> no divergence

    int A0[2], A1[2], B0[2], B1[2];
    float W0[2], W1[2], W2[2], W3[2];
#pragma unroll
    for (int j = 0; j < 2; ++j) {
        const int t = t0 + j;
        int k0, k1; float lam;
        if (identity) {
            // sc = (t+0.5)*1.0 - 0.5 == t exactly in fp32 -> lam == 0
            k0 = t; k1 = t; lam = 0.f;
        } else {
            float sc = fmaxf(((float)t + 0.5f) * ((float)T_total / (float)TOUT) - 0.5f, 0.f);
            k0 = (int)floorf(sc);
            k1 = min(k0 + 1, T_total - 1);
            lam = sc - (float)k0;
        }
        int a0, a1, bb0, bb1; float wa, wb;
        map_concat(k0, cum16, wbp, n_segs, a0, a1, wa);
        if (identity) { bb0 = a0; bb1 = a1; wb = wa; }
        else          map_concat(k1, cum16, wbp, n_segs, bb0, bb1, wb);
        A0[j] = a0; A1[j] = a1; B0[j] = bb0; B1[j] = bb1;
        W0[j] = (1.f - lam) * (1.f - wa);
        W1[j] = (1.f - lam) * wa;
        W2[j] = lam * (1.f - wb);
        W3[j] = lam * wb;
    }

    // block input window: map is monotone in t, so extremes live at threads 0 / 255
    if (tid == 0)   bcast[0] = A0[0];
    if (tid == 255) bcast[1] = max(A1[1], B1[1]);
    __syncthreads();
    const int x_lo = bcast[0] & ~3;             // align for float4 staging
    const int x_hi = bcast[1];
    const int n4 = (x_hi + 1 - x_lo + 3) >> 2;  // float4s per f-row

    if (n4 <= SPAN4) {
        // ---- fast path: reg-staged double-buffered LDS window ----
        const int row = tid >> 5;               // 8 rows x 32 threads
        const int c0  = tid & 31;
        const int a0r0 = A0[0] - x_lo, b0r0 = B0[0] - x_lo;
        const int a0r1 = A0[1] - x_lo, b0r1 = B0[1] - x_lo;
        // a1 is provably a0 or a0+1 (clamp stays inside the segment):
        // read the adjacent pair with one ds_read2 and select the clamped case away.
        const bool sa0 = (A1[0] == A0[0] + 1), sb0 = (B1[0] == B0[0] + 1);
        const bool sa1 = (A1[1] == A0[1] + 1), sb1 = (B1[1] == B0[1] + 1);

        f32x4 R[4];
#define STAGE_LOAD(ch)                                                                    \
        { const f32x4* gs = (const f32x4*)(mel + ((size_t)(b * FIN + fz + (ch) * FG + row)) * TIN + x_lo); \
          _Pragma("unroll")                                                               \
          for (int k = 0; k < 4; ++k) { int c = c0 + 32 * k; if (c < n4) R[k] = gs[c]; } }
#define STAGE_WRITE(buf)                                                                  \
        { f32x4* ds = (f32x4*)(stage[buf] + row * SPANP);                                 \
          _Pragma("unroll")                                                               \
          for (int k = 0; k < 4; ++k) { int c = c0 + 32 * k; if (c < n4) ds[c] = R[k]; } }

        STAGE_LOAD(0)
        STAGE_WRITE(0)
        __syncthreads();

        for (int ch = 0; ch < NCH; ++ch) {
            const int cur = ch & 1;
            if (ch + 1 < NCH) STAGE_LOAD(ch + 1)          // issue early; waitcnt lands at STAGE_WRITE

            float* ob = out + ((size_t)(b * FOUT + fz + ch * FG)) * TOUT + t0;
            if (identity) {
#pragma unroll
                for (int f = 0; f < FG; ++f) {
                    const float* Lp = stage[cur] + f * SPANP;
                    float xa0 = Lp[a0r0], ya0 = Lp[a0r0 + 1];   // merges to ds_read2_b32
                    float xa1 = Lp[a0r1], ya1 = Lp[a0r1 + 1];
                    f32x2 v;
                    v.x = W0[0] * xa0 + W1[0] * (sa0 ? ya0 : xa0);
                    v.y = W0[1] * xa1 + W1[1] * (sa1 ? ya1 : xa1);
                    __builtin_nontemporal_store(v, (f32x2*)(ob + (size_t)f * TOUT));
                }
            } else {
#pragma unroll
                for (int f = 0; f < FG; ++f) {
                    const float* Lp = stage[cur] + f * SPANP;
                    float xa0 = Lp[a0r0], ya0 = Lp[a0r0 + 1];
                    float xa1 = Lp[a0r1], ya1 = Lp[a0r1 + 1];
                    float xb0 = Lp[b0r0], yb0 = Lp[b0r0 + 1];
                    float xb1 = Lp[b0r1], yb1 = Lp[b0r1 + 1];
                    f32x2 v;
                    v.x = W0[0] * xa0 + W1[0] * (sa0 ? ya0 : xa0) + W2[0] * xb0 + W3[0] * (sb0 ? yb0 : xb0);
                    v.y = W0[1] * xa1 + W1[1] * (sa1 ? ya1 : xa1) + W2[1] * xb1 + W3[1] * (sb1 ? yb1 : xb1);
                    __builtin_nontemporal_store(v, (f32x2*)(ob + (size_t)f * TOUT));
                }
            }

            if (ch + 1 < NCH) STAGE_WRITE(cur ^ 1)        // write other half; readers of cur already done
            __syncthreads();
        }
#undef STAGE_LOAD
#undef STAGE_WRITE
    } else {
        // ---- fallback (pathological span): direct global gathers ----
        const float* mb = mel + (size_t)b * FIN * TIN;
        float* ob = out + ((size_t)(b * FOUT + fz)) * TOUT + t0;
#pragma unroll 4
        for (int f = 0; f < FPB; ++f) {
            const float* r = mb + (size_t)(fz + f) * TIN;
            ob[(size_t)f * TOUT + 0] = W0[0] * r[A0[0]] + W1[0] * r[A1[0]] + W2[0] * r[B0[0]] + W3[0] * r[B1[0]];
            ob[(size_t)f * TOUT + 1] = W0[1] * r[A0[1]] + W1[1] * r[A1[1]] + W2[1] * r[B0[1]] + W3[1] * r[B1[1]];
        }
    }
}

extern "C" void kernel_launch(void* const* d_in, const int* in_sizes, int n_in,
                              void* d_out, int out_size, void* d_ws, size_t ws_size,
                              hipStream_t stream) {
    const float* mel = (const float*)d_in[0];
    const int* mask  = (const int*)d_in[1];
    float* out = (float*)d_out;
    int* ws = (int*)d_ws;

    seg_kernel<<<NB, 256, 0, stream>>>(mask, ws);

    dim3 grid(TOUT / TB, NB, ZSPL);
    resample_kernel<<<grid, 256, 0, stream>>>(mel, ws, out);
}